// Round 17
// baseline (1179.856 us; speedup 1.0000x reference)
//
#include <hip/hip_runtime.h>
#include <math.h>

// BracketNet: ctx_{s+1} = GELU(Wc·ctx_s + (b + Wx·x_s)); out_s = x_s + ctx_{s+1}
// pass1: z = b + Wx·x, parallel, LDS-broadcast pk_fma GEMV.
// pass2: serial chain, one wave per (b,h); LDS-broadcast engine:
//        ds_write g -> 16 uniform ds_read_b128 (broadcast) -> 32 v_pk_fma_f32
//        (full-rate packed fp32) -> pk_add reduce -> 3-term erf gelu.
//        Volatile-asm global loads/stores + counted vmcnt (depth 8) keep the
//        x/z streams 7 steps ahead (r14 lesson: plain-C prefetch gets sunk).
//
// r16 postmortem: readlane+dot2 floor = 64 VALU insts/step + slow SGPR-write
// readlanes -> 478 cyc/step. r9's LDS verdict (1100) was confounded by the
// load-sinking bug. pk_fma engine: no readlane, no pack, fp32 end-to-end.

typedef float    f32x4 __attribute__((ext_vector_type(4)));
typedef float    f32x2 __attribute__((ext_vector_type(2)));

#define S_LEN 2048
#define B_SZ  64
#define D_SZ  512
#define DIM   64
#define STRIDE ((size_t)(B_SZ * D_SZ))   // floats between consecutive s

// v_pk_fma_f32: D = A*B + C on 2 packed fp32 (full rate on gfx950).
__device__ __forceinline__ f32x2 pkfma(f32x2 a, f32x2 b, f32x2 c) {
    f32x2 d;
    asm("v_pk_fma_f32 %0, %1, %2, %3" : "=v"(d) : "v"(a), "v"(b), "v"(c));
    return d;
}

// y[lane] = base + sum_k w[lane][k]*vv[k], vv = uniform LDS pointer
// (broadcast reads). 16 ds_read_b128 + 32 pk_fma + 7 pk_add + 1 add.
__device__ __forceinline__ float gemv64pk(const f32x4* vv, const f32x4 (&w)[16],
                                          float base) {
    f32x2 A0 = {base, 0.f}, A1 = {0.f, 0.f}, A2 = {0.f, 0.f}, A3 = {0.f, 0.f};
    f32x2 A4 = {0.f, 0.f},  A5 = {0.f, 0.f}, A6 = {0.f, 0.f}, A7 = {0.f, 0.f};
#define Q4(jq, Aa, Ab)                                                        \
    do {                                                                      \
        const f32x4 q   = vv[jq];                                             \
        const f32x2 qlo = __builtin_shufflevector(q, q, 0, 1);                \
        const f32x2 qhi = __builtin_shufflevector(q, q, 2, 3);                \
        const f32x4 ww  = w[jq];                                              \
        const f32x2 wlo = __builtin_shufflevector(ww, ww, 0, 1);              \
        const f32x2 whi = __builtin_shufflevector(ww, ww, 2, 3);              \
        Aa = pkfma(wlo, qlo, Aa);                                             \
        Ab = pkfma(whi, qhi, Ab);                                             \
    } while (0)
    Q4(0, A0, A1);  Q4(1, A2, A3);  Q4(2, A4, A5);  Q4(3, A6, A7);
    Q4(4, A0, A1);  Q4(5, A2, A3);  Q4(6, A4, A5);  Q4(7, A6, A7);
    Q4(8, A0, A1);  Q4(9, A2, A3);  Q4(10, A4, A5); Q4(11, A6, A7);
    Q4(12, A0, A1); Q4(13, A2, A3); Q4(14, A4, A5); Q4(15, A6, A7);
#undef Q4
    const f32x2 s = ((A0 + A1) + (A2 + A3)) + ((A4 + A5) + (A6 + A7));
    return s.x + s.y;
}

// 3-term A&S 7.1.25 erf gelu (|eps|<=2.5e-5), fma-combined tail.
__device__ __forceinline__ float gelu_fast(float y) {
    const float ax = fabsf(y) * 0.70710678118654752440f;
    const float t  = __builtin_amdgcn_rcpf(fmaf(0.47047f, ax, 1.0f));
    const float e  = __builtin_amdgcn_exp2f(-ax * ax * 1.44269504088896f);
    float p = fmaf(0.7478556f, t, -0.0958798f);
    p = fmaf(p, t, 0.3480242f);
    p *= t;
    float er = fmaf(-p, e, 1.0f);
    er = copysignf(er, y);
    const float m = 0.5f * y;
    return fmaf(m, er, m);
}

// ---------------- Pass 1: z = b + Wx·x, one wave per (b,h,128-s chunk).
__global__ __launch_bounds__(64, 1) void bracket_pass1(
    const float* __restrict__ src, const float* __restrict__ W,
    const float* __restrict__ bias, float* __restrict__ zout)
{
    const int lane = threadIdx.x;
    const int ck   = blockIdx.x >> 9;          // 0..15 (128 s each)
    const int bb   = (blockIdx.x >> 3) & 63;
    const int hh   = blockIdx.x & 7;

    f32x4 w[16];
    {
        const float* wb = W + (size_t)(hh * DIM + lane) * (2 * DIM) + DIM;
#pragma unroll
        for (int i = 0; i < 16; ++i)
            asm volatile("global_load_dwordx4 %0, %1, off offset:%2"
                         : "=v"(w[i]) : "v"(wb), "i"(16 * i));
    }
    asm volatile("s_waitcnt vmcnt(0)" ::: "memory");
    __builtin_amdgcn_sched_barrier(0);

    const float bv = bias[hh * DIM + lane];

    __shared__ __align__(16) float xsl[2][DIM];   // 512 B ping-pong

    const float* sp = src  + (size_t)(ck * 128) * STRIDE + (size_t)bb * D_SZ + hh * DIM + lane;
    float*       zp = zout + (size_t)(ck * 128) * STRIDE + (size_t)bb * D_SZ + hh * DIM + lane;

    float x0 = sp[0], x1 = sp[STRIDE];
    const float* pp    = sp + 2 * STRIDE;
    const float* plast = sp + 127 * STRIDE;

#define P1STEP(cur, xc)                                                       \
    do {                                                                      \
        xsl[cur][lane] = xc;                                                  \
        const float xn = *pp;                                                 \
        pp = (pp < plast) ? (pp + STRIDE) : plast;                            \
        const float y = gemv64pk((const f32x4*)xsl[cur], w, bv);              \
        *zp = y;                                                              \
        zp += STRIDE;                                                         \
        xc = xn;                                                              \
    } while (0)

    for (int i = 0; i < 128; i += 2) {
        P1STEP(0, x0);
        P1STEP(1, x1);
    }
#undef P1STEP
}

// ---------------- Pass 2: serial chain, LDS-broadcast pk_fma GEMV,
// depth-8 counted-vmcnt volatile-asm global pipeline.
#define GLOAD(dst, ptr) \
    asm volatile("global_load_dword %0, %1, off" : "=v"(dst) : "v"(ptr))
#define GSTORE(val, ptr) \
    asm volatile("global_store_dword %1, %0, off" : : "v"(val), "v"(ptr) : "memory")

__global__ __launch_bounds__(64, 1) void bracket_pass2(
    const float* __restrict__ src, const float* __restrict__ W,
    float* __restrict__ out)   // out holds z on entry; overwritten with result
{
    const int lane = threadIdx.x;
    const int bb   = blockIdx.x >> 3;
    const int hh   = blockIdx.x & 7;

    // Wc row fp32: 16 float4 = 64 VGPRs, pinned (volatile asm).
    f32x4 w[16];
    {
        const float* wb = W + (size_t)(hh * DIM + lane) * (2 * DIM);
#pragma unroll
        for (int i = 0; i < 16; ++i)
            asm volatile("global_load_dwordx4 %0, %1, off offset:%2"
                         : "=v"(w[i]) : "v"(wb), "i"(16 * i));
    }
    asm volatile("s_waitcnt vmcnt(0)" ::: "memory");
    __builtin_amdgcn_sched_barrier(0);

    __shared__ __align__(16) float gbuf[2][DIM];  // 512 B ping-pong

    const float* sp = src + (size_t)bb * D_SZ + hh * DIM + lane;
    float*       op = out + (size_t)bb * D_SZ + hh * DIM + lane;  // store ptr
    const float* px = sp;                                         // x load ptr
    const float* pz = op;                                         // z load ptr

    float xb[8], zb[8];
    float g = 0.0f;   // ctx_0 = 0

    // Prologue: 16 loads, per-slot order x_i, z_i.
#pragma unroll
    for (int i = 0; i < 8; ++i) {
        GLOAD(xb[i], px); px += STRIDE;
        GLOAD(zb[i], pz); pz += STRIDE;
    }

#define STEP_CORE(i)                                                          \
    do {                                                                      \
        gbuf[(i) & 1][lane] = g;            /* ds_write_b32 (serial path) */  \
        const float y = gemv64pk((const f32x4*)gbuf[(i) & 1], w, zb[i]);      \
        g = gelu_fast(y);                                                     \
        const float r = xb[i] + g;                                            \
        GSTORE(r, op);                                                        \
        op += STRIDE;                                                         \
    } while (0)

#define STEPL(i, N)                                                           \
    do {                                                                      \
        asm volatile("s_waitcnt vmcnt(" #N ")");                              \
        __builtin_amdgcn_sched_barrier(0);                                    \
        STEP_CORE(i);                                                         \
        GLOAD(xb[i], px); px += STRIDE;                                       \
        GLOAD(zb[i], pz); pz += STRIDE;                                       \
    } while (0)

#define STEPE(i, N)                                                           \
    do {                                                                      \
        asm volatile("s_waitcnt vmcnt(" #N ")");                              \
        __builtin_amdgcn_sched_barrier(0);                                    \
        STEP_CORE(i);                                                         \
    } while (0)

    // vmcnt accounting, 3 vmem/step (store, load x, load z), depth 8:
    // fill steps 0..7: slot-i loads trailed by 2*(7-i) prologue + 3*i step ops.
    STEPL(0, 14); STEPL(1, 15); STEPL(2, 16); STEPL(3, 17);
    STEPL(4, 18); STEPL(5, 19); STEPL(6, 20); STEPL(7, 21);
    // steady state: slot loads trailed by 7 full steps = 21 ops.
    for (int blk = 0; blk < 254; ++blk) {
        STEPL(0, 21); STEPL(1, 21); STEPL(2, 21); STEPL(3, 21);
        STEPL(4, 21); STEPL(5, 21); STEPL(6, 21); STEPL(7, 21);
    }
    // drain steps 2040..2047: N = 21 - 2i.
    STEPE(0, 21); STEPE(1, 19); STEPE(2, 17); STEPE(3, 15);
    STEPE(4, 13); STEPE(5, 11); STEPE(6, 9);  STEPE(7, 7);

#undef STEPL
#undef STEPE
#undef STEP_CORE
}

extern "C" void kernel_launch(void* const* d_in, const int* in_sizes, int n_in,
                              void* d_out, int out_size, void* d_ws, size_t ws_size,
                              hipStream_t stream) {
    const float* src = (const float*)d_in[0];
    const float* W   = (const float*)d_in[1];
    const float* b   = (const float*)d_in[2];
    float* out       = (float*)d_out;

    hipLaunchKernelGGL(bracket_pass1, dim3(B_SZ * 8 * 16), dim3(64), 0, stream,
                       src, W, b, out);
    hipLaunchKernelGGL(bracket_pass2, dim3(B_SZ * 8), dim3(64), 0, stream,
                       src, W, out);
}

// Round 18
// 537.944 us; speedup vs baseline: 2.1933x; 2.1933x over previous
//
#include <hip/hip_runtime.h>
#include <math.h>

// BracketNet: ctx_{s+1} = GELU(Wc·ctx_s + (b + Wx·x_s)); out_s = x_s + ctx_{s+1}
// pass1: z = b + Wx·x, parallel (issue-bound at 8 waves/SIMD): x packed to
//        f16 pairs (DPP+pkrtz, even lanes), 1 LDS dword write, 8 uniform
//        ds_read_b128, 32 v_dot2_f32_f16. ~50 insts/step.
// pass2: serial chain (r16 engine, 478 cyc/step — best measured): 32-RL
//        batch + one fence + 32 dot2, depth-8 counted-vmcnt volatile-asm
//        global pipeline, 3-term erf gelu.
//
// Broadcast-primitive scoreboard for the SERIAL path (cyc/step, measured):
// readlane+dot2 478 < readlane+fma 535 < bpermute+MFMA 1078 < LDS roundtrip
// ~1100-1180 (r9/r17 — lgkm-chained write->read, nothing overlaps at 1
// wave/SIMD). LDS broadcast is only viable at high occupancy (pass1).

typedef float    f32x4 __attribute__((ext_vector_type(4)));
typedef int      i32x4 __attribute__((ext_vector_type(4)));
typedef _Float16 f16x2 __attribute__((ext_vector_type(2)));

#define S_LEN 2048
#define B_SZ  64
#define D_SZ  512
#define DIM   64
#define STRIDE ((size_t)(B_SZ * D_SZ))   // floats between consecutive s

__device__ __forceinline__ int pkrtz(float a, float b) {
    return __builtin_bit_cast(int, __builtin_amdgcn_cvt_pkrtz(a, b));
}

__device__ __forceinline__ float fdot2h(int pack, int wpk, float acc) {
#if __has_builtin(__builtin_amdgcn_fdot2)
    return __builtin_amdgcn_fdot2(__builtin_bit_cast(f16x2, pack),
                                  __builtin_bit_cast(f16x2, wpk), acc, false);
#else
    float d;
    asm("v_dot2_f32_f16 %0, %1, %2, %3"
        : "=v"(d)
        : "v"(__builtin_bit_cast(f16x2, pack)),
          "v"(__builtin_bit_cast(f16x2, wpk)), "v"(acc));
    return d;
#endif
}

// 3-term A&S 7.1.25 erf gelu (|eps|<=2.5e-5), fma-combined tail.
__device__ __forceinline__ float gelu_fast(float y) {
    const float ax = fabsf(y) * 0.70710678118654752440f;
    const float t  = __builtin_amdgcn_rcpf(fmaf(0.47047f, ax, 1.0f));
    const float e  = __builtin_amdgcn_exp2f(-ax * ax * 1.44269504088896f);
    float p = fmaf(0.7478556f, t, -0.0958798f);
    p = fmaf(p, t, 0.3480242f);
    p *= t;
    float er = fmaf(-p, e, 1.0f);
    er = copysignf(er, y);
    const float m = 0.5f * y;
    return fmaf(m, er, m);
}

// ---------------- Pass 1: z = b + Wx·x, one wave per (b,h,128-s chunk).
// Packed-f16 LDS broadcast + dot2 (issue-bound; LDS latency hidden by TLP).
__global__ __launch_bounds__(64, 1) void bracket_pass1(
    const float* __restrict__ src, const float* __restrict__ W,
    const float* __restrict__ bias, float* __restrict__ zout)
{
    const int lane = threadIdx.x;
    const int ck   = blockIdx.x >> 9;          // 0..15 (128 s each)
    const int bb   = (blockIdx.x >> 3) & 63;
    const int hh   = blockIdx.x & 7;

    // Wx row fp32 (pinned), packed to f16 pairs: wp[p] = (Wx[d][2p], Wx[d][2p+1]).
    f32x4 w[16];
    {
        const float* wb = W + (size_t)(hh * DIM + lane) * (2 * DIM) + DIM;
#pragma unroll
        for (int i = 0; i < 16; ++i)
            asm volatile("global_load_dwordx4 %0, %1, off offset:%2"
                         : "=v"(w[i]) : "v"(wb), "i"(16 * i));
    }
    asm volatile("s_waitcnt vmcnt(0)" ::: "memory");
    __builtin_amdgcn_sched_barrier(0);

    int wp[32];
#pragma unroll
    for (int j = 0; j < 16; ++j) {
        wp[2 * j]     = pkrtz(w[j].x, w[j].y);
        wp[2 * j + 1] = pkrtz(w[j].z, w[j].w);
    }

    const float bv = bias[hh * DIM + lane];

    // Slots 0..31 = packed pairs; 32..63 = dummy sink for odd lanes
    // (even lane 2k -> slot k; per-bank 2-way access = free).
    __shared__ __align__(16) int xpk[2][2 * DIM];
    const int wslot = (lane >> 1) | ((lane & 1) << 5);

    const float* sp = src  + (size_t)(ck * 128) * STRIDE + (size_t)bb * D_SZ + hh * DIM + lane;
    float*       zp = zout + (size_t)(ck * 128) * STRIDE + (size_t)bb * D_SZ + hh * DIM + lane;

    float x0 = sp[0], x1 = sp[STRIDE];
    const float* pp    = sp + 2 * STRIDE;
    const float* plast = sp + 127 * STRIDE;

#define P1STEP(cur, xc)                                                       \
    do {                                                                      \
        const int xi  = __float_as_int(xc);                                   \
        const int xsh = __builtin_amdgcn_mov_dpp(xi, 0x101, 0xf, 0xf, true);  \
        xpk[cur][wslot] = pkrtz(xc, __int_as_float(xsh));                     \
        const float xn = *pp;                                                 \
        pp = (pp < plast) ? (pp + STRIDE) : plast;                            \
        const i32x4* vv = (const i32x4*)xpk[cur];                             \
        float a0 = bv, a1 = 0.f, a2 = 0.f, a3 = 0.f;                          \
        float a4 = 0.f, a5 = 0.f, a6 = 0.f, a7 = 0.f;                         \
        _Pragma("unroll")                                                     \
        for (int j = 0; j < 8; j += 2) {                                      \
            const i32x4 u0 = vv[j], u1 = vv[j + 1];                           \
            a0 = fdot2h(u0.x, wp[4 * j + 0], a0);                             \
            a1 = fdot2h(u0.y, wp[4 * j + 1], a1);                             \
            a2 = fdot2h(u0.z, wp[4 * j + 2], a2);                             \
            a3 = fdot2h(u0.w, wp[4 * j + 3], a3);                             \
            a4 = fdot2h(u1.x, wp[4 * j + 4], a4);                             \
            a5 = fdot2h(u1.y, wp[4 * j + 5], a5);                             \
            a6 = fdot2h(u1.z, wp[4 * j + 6], a6);                             \
            a7 = fdot2h(u1.w, wp[4 * j + 7], a7);                             \
        }                                                                     \
        *zp = ((a0 + a1) + (a2 + a3)) + ((a4 + a5) + (a6 + a7));              \
        zp += STRIDE;                                                         \
        xc = xn;                                                              \
    } while (0)

    for (int i = 0; i < 128; i += 2) {
        P1STEP(0, x0);
        P1STEP(1, x1);
    }
#undef P1STEP
}

// ---------------- Pass 2 (r16 engine, verbatim): serial chain, single 32-RL
// batch dot2 GEMV, depth-8 counted-vmcnt volatile-asm prefetch.
#define GLOAD(dst, ptr) \
    asm volatile("global_load_dword %0, %1, off" : "=v"(dst) : "v"(ptr))
#define GSTORE(val, ptr) \
    asm volatile("global_store_dword %1, %0, off" : : "v"(val), "v"(ptr) : "memory")

#define DOT32()                                                               \
    do {                                                                      \
        const int t0  = __builtin_amdgcn_readlane(gpi, 0);                    \
        const int t1  = __builtin_amdgcn_readlane(gpi, 2);                    \
        const int t2  = __builtin_amdgcn_readlane(gpi, 4);                    \
        const int t3  = __builtin_amdgcn_readlane(gpi, 6);                    \
        const int t4  = __builtin_amdgcn_readlane(gpi, 8);                    \
        const int t5  = __builtin_amdgcn_readlane(gpi, 10);                   \
        const int t6  = __builtin_amdgcn_readlane(gpi, 12);                   \
        const int t7  = __builtin_amdgcn_readlane(gpi, 14);                   \
        const int t8  = __builtin_amdgcn_readlane(gpi, 16);                   \
        const int t9  = __builtin_amdgcn_readlane(gpi, 18);                   \
        const int t10 = __builtin_amdgcn_readlane(gpi, 20);                   \
        const int t11 = __builtin_amdgcn_readlane(gpi, 22);                   \
        const int t12 = __builtin_amdgcn_readlane(gpi, 24);                   \
        const int t13 = __builtin_amdgcn_readlane(gpi, 26);                   \
        const int t14 = __builtin_amdgcn_readlane(gpi, 28);                   \
        const int t15 = __builtin_amdgcn_readlane(gpi, 30);                   \
        const int t16 = __builtin_amdgcn_readlane(gpi, 32);                   \
        const int t17 = __builtin_amdgcn_readlane(gpi, 34);                   \
        const int t18 = __builtin_amdgcn_readlane(gpi, 36);                   \
        const int t19 = __builtin_amdgcn_readlane(gpi, 38);                   \
        const int t20 = __builtin_amdgcn_readlane(gpi, 40);                   \
        const int t21 = __builtin_amdgcn_readlane(gpi, 42);                   \
        const int t22 = __builtin_amdgcn_readlane(gpi, 44);                   \
        const int t23 = __builtin_amdgcn_readlane(gpi, 46);                   \
        const int t24 = __builtin_amdgcn_readlane(gpi, 48);                   \
        const int t25 = __builtin_amdgcn_readlane(gpi, 50);                   \
        const int t26 = __builtin_amdgcn_readlane(gpi, 52);                   \
        const int t27 = __builtin_amdgcn_readlane(gpi, 54);                   \
        const int t28 = __builtin_amdgcn_readlane(gpi, 56);                   \
        const int t29 = __builtin_amdgcn_readlane(gpi, 58);                   \
        const int t30 = __builtin_amdgcn_readlane(gpi, 60);                   \
        const int t31 = __builtin_amdgcn_readlane(gpi, 62);                   \
        __builtin_amdgcn_sched_barrier(0);                                    \
        a0 = fdot2h(t0,  wp[0],  a0);  a1 = fdot2h(t1,  wp[1],  a1);          \
        a2 = fdot2h(t2,  wp[2],  a2);  a3 = fdot2h(t3,  wp[3],  a3);          \
        a4 = fdot2h(t4,  wp[4],  a4);  a5 = fdot2h(t5,  wp[5],  a5);          \
        a6 = fdot2h(t6,  wp[6],  a6);  a7 = fdot2h(t7,  wp[7],  a7);          \
        a0 = fdot2h(t8,  wp[8],  a0);  a1 = fdot2h(t9,  wp[9],  a1);          \
        a2 = fdot2h(t10, wp[10], a2);  a3 = fdot2h(t11, wp[11], a3);          \
        a4 = fdot2h(t12, wp[12], a4);  a5 = fdot2h(t13, wp[13], a5);          \
        a6 = fdot2h(t14, wp[14], a6);  a7 = fdot2h(t15, wp[15], a7);          \
        a0 = fdot2h(t16, wp[16], a0);  a1 = fdot2h(t17, wp[17], a1);          \
        a2 = fdot2h(t18, wp[18], a2);  a3 = fdot2h(t19, wp[19], a3);          \
        a4 = fdot2h(t20, wp[20], a4);  a5 = fdot2h(t21, wp[21], a5);          \
        a6 = fdot2h(t22, wp[22], a6);  a7 = fdot2h(t23, wp[23], a7);          \
        a0 = fdot2h(t24, wp[24], a0);  a1 = fdot2h(t25, wp[25], a1);          \
        a2 = fdot2h(t26, wp[26], a2);  a3 = fdot2h(t27, wp[27], a3);          \
        a4 = fdot2h(t28, wp[28], a4);  a5 = fdot2h(t29, wp[29], a5);          \
        a6 = fdot2h(t30, wp[30], a6);  a7 = fdot2h(t31, wp[31], a7);          \
    } while (0)

__global__ __launch_bounds__(64, 1) void bracket_pass2(
    const float* __restrict__ src, const float* __restrict__ W,
    float* __restrict__ out)   // out holds z on entry; overwritten with result
{
    const int lane = threadIdx.x;
    const int bb   = blockIdx.x >> 3;
    const int hh   = blockIdx.x & 7;

    f32x4 w[16];
    {
        const float* wb = W + (size_t)(hh * DIM + lane) * (2 * DIM);
#pragma unroll
        for (int i = 0; i < 16; ++i)
            asm volatile("global_load_dwordx4 %0, %1, off offset:%2"
                         : "=v"(w[i]) : "v"(wb), "i"(16 * i));
    }
    asm volatile("s_waitcnt vmcnt(0)" ::: "memory");
    __builtin_amdgcn_sched_barrier(0);

    int wp[32];
#pragma unroll
    for (int j = 0; j < 16; ++j) {
        wp[2 * j]     = pkrtz(w[j].x, w[j].y);
        wp[2 * j + 1] = pkrtz(w[j].z, w[j].w);
    }

    const float* sp = src + (size_t)bb * D_SZ + hh * DIM + lane;
    float*       op = out + (size_t)bb * D_SZ + hh * DIM + lane;  // store ptr
    const float* px = sp;                                         // x load ptr
    const float* pz = op;                                         // z load ptr

    float xb[8], zb[8];
    float g = 0.0f;   // ctx_0 = 0

#pragma unroll
    for (int i = 0; i < 8; ++i) {
        GLOAD(xb[i], px); px += STRIDE;
        GLOAD(zb[i], pz); pz += STRIDE;
    }

#define STEP_CORE(i)                                                          \
    do {                                                                      \
        const float zi = zb[i];                                               \
        const int gi  = __float_as_int(g);                                    \
        const int gsh = __builtin_amdgcn_mov_dpp(gi, 0x101, 0xf, 0xf, true);  \
        const int gpi = pkrtz(g, __int_as_float(gsh));                        \
        float a0 = zi, a1 = 0.f, a2 = 0.f, a3 = 0.f;                          \
        float a4 = 0.f, a5 = 0.f, a6 = 0.f, a7 = 0.f;                         \
        DOT32();                                                              \
        const float y = ((a0 + a1) + (a2 + a3)) + ((a4 + a5) + (a6 + a7));    \
        g = gelu_fast(y);                                                     \
        const float r = xb[i] + g;                                            \
        GSTORE(r, op);                                                        \
        op += STRIDE;                                                         \
    } while (0)

#define STEPL(i, N)                                                           \
    do {                                                                      \
        asm volatile("s_waitcnt vmcnt(" #N ")");                              \
        __builtin_amdgcn_sched_barrier(0);                                    \
        STEP_CORE(i);                                                         \
        GLOAD(xb[i], px); px += STRIDE;                                       \
        GLOAD(zb[i], pz); pz += STRIDE;                                       \
    } while (0)

#define STEPE(i, N)                                                           \
    do {                                                                      \
        asm volatile("s_waitcnt vmcnt(" #N ")");                              \
        __builtin_amdgcn_sched_barrier(0);                                    \
        STEP_CORE(i);                                                         \
    } while (0)

    STEPL(0, 14); STEPL(1, 15); STEPL(2, 16); STEPL(3, 17);
    STEPL(4, 18); STEPL(5, 19); STEPL(6, 20); STEPL(7, 21);
    for (int blk = 0; blk < 254; ++blk) {
        STEPL(0, 21); STEPL(1, 21); STEPL(2, 21); STEPL(3, 21);
        STEPL(4, 21); STEPL(5, 21); STEPL(6, 21); STEPL(7, 21);
    }
    STEPE(0, 21); STEPE(1, 19); STEPE(2, 17); STEPE(3, 15);
    STEPE(4, 13); STEPE(5, 11); STEPE(6, 9);  STEPE(7, 7);

#undef STEPL
#undef STEPE
#undef STEP_CORE
}

extern "C" void kernel_launch(void* const* d_in, const int* in_sizes, int n_in,
                              void* d_out, int out_size, void* d_ws, size_t ws_size,
                              hipStream_t stream) {
    const float* src = (const float*)d_in[0];
    const float* W   = (const float*)d_in[1];
    const float* b   = (const float*)d_in[2];
    float* out       = (float*)d_out;

    hipLaunchKernelGGL(bracket_pass1, dim3(B_SZ * 8 * 16), dim3(64), 0, stream,
                       src, W, b, out);
    hipLaunchKernelGGL(bracket_pass2, dim3(B_SZ * 8), dim3(64), 0, stream,
                       src, W, out);
}